// Round 4
// baseline (207.115 us; speedup 1.0000x reference)
//
#include <hip/hip_runtime.h>
#include <math.h>

#define D 512
#define NC 64
#define NQ 2048
#define NR 448   // 384 U rows + 64 MU rows
#define MT (NR + NQ)   // 2496 combined GEMM rows

// ---- workspace float offsets ----
#define OFF_S    0
#define OFF_L    32
#define OFF_W    (OFF_L + D*D)
#define OFF_TMP  (OFF_W + D*D)          // 256*256 max doubling temp
#define OFF_UB   (OFF_TMP + 65536)      // [U(384); MU(64)] : NR x D
#define OFF_YY   (OFF_UB + NR*D)        // [UW(384); MW(64); Y(2048)] : MT x D
#define OFF_T2   (OFF_YY + MT*D)        // NQ x NR
#define OFF_MINV (OFF_T2 + NQ*NR)       // NC*36
#define OFF_BIAS (OFF_MINV + NC*36)
#define OFF_H    (OFF_BIAS + NC)
#define OFF_AQ   (OFF_H + NC)
#define OFF_SV   (OFF_AQ + NQ)          // NC*6

__device__ inline float wred(float v) {
#pragma unroll
  for (int off = 32; off; off >>= 1) v += __shfl_down(v, off);
  return v;  // lane 0 holds sum
}

// Fused prep: blocks 0..1023 build L (+zero W upper), 1024..1087 classprep,
// 1088 computes the shared scalars.
__global__ __launch_bounds__(256) void k_prep(const float* __restrict__ diag,
                                              const float* __restrict__ low,
                                              const float* __restrict__ Xs,
                                              const float* __restrict__ m,
                                              const float* __restrict__ kp,
                                              const float* __restrict__ nup,
                                              float* __restrict__ L, float* __restrict__ W,
                                              float* __restrict__ Ub, float* __restrict__ S) {
  int bid = blockIdx.x, tid = threadIdx.x;
  if (bid < 1024) {
    int t = bid * 256 + tid;
    int i = t / D, j = t % D;
    float v;
    if (i == j)      v = fabsf(diag[i]);
    else if (i > j)  v = low[t];
    else             v = 0.f;
    L[t] = v;
    if (i < j) W[t] = 0.f;
  } else if (bid < 1088) {
    int c = bid - 1024;
    float kappa = kp[0];
    float kn = fabsf(kappa) + 1e-6f + 5.0f;
    float xw = 5.0f / kn;
    float mw = fabsf(kappa + 1e-6f) / kn;
    float sw = sqrtf((fabsf(kappa) + 1e-6f) / kn);
    const float is5 = 0.44721359549995793f;  // 1/sqrt(5)
    for (int d = tid; d < D; d += 256) {
      float x0 = Xs[(size_t)(c * 5 + 0) * D + d];
      float x1 = Xs[(size_t)(c * 5 + 1) * D + d];
      float x2 = Xs[(size_t)(c * 5 + 2) * D + d];
      float x3 = Xs[(size_t)(c * 5 + 3) * D + d];
      float x4 = Xs[(size_t)(c * 5 + 4) * D + d];
      float xm = (x0 + x1 + x2 + x3 + x4) * 0.2f;
      float mv = m[d];
      Ub[(size_t)(c * 6 + 0) * D + d] = x0 * is5;
      Ub[(size_t)(c * 6 + 1) * D + d] = x1 * is5;
      Ub[(size_t)(c * 6 + 2) * D + d] = x2 * is5;
      Ub[(size_t)(c * 6 + 3) * D + d] = x3 * is5;
      Ub[(size_t)(c * 6 + 4) * D + d] = x4 * is5;
      Ub[(size_t)(c * 6 + 5) * D + d] = sw * (xm - mv);
      Ub[(size_t)(384 + c) * D + d]   = mw * mv + xw * xm;
    }
  } else {
    if (tid >= 64) return;
    int lane = tid;
    float part = 0.f;
    for (int i = lane; i < D; i += 64) part += logf(fabsf(diag[i]));
    part = wred(part);
    if (lane != 0) return;
    float lda = 2.f * part;
    float kappa = kp[0], nu = nup[0];
    float kn = fabsf(kappa) + 1e-6f + 5.0f;
    float sp = fmaxf(nu, (float)(D - 1) + 1e-6f) + 5.0f - (float)D + 2.0f;
    float bias_shared = lgammaf(0.5f * (sp + (float)D)) - lgammaf(0.5f * sp)
                      - 0.5f * (float)D * logf(sp);
    float scale = kn * sp / (kn + 1.0f);
    S[0] = kn; S[1] = sp; S[2] = scale; S[3] = bias_shared;
    S[8] = 1.f / scale;
    S[9] = (float)D * logf(scale) + lda;
    S[10] = 0.5f * (sp + (float)D);
    S[11] = 1.f / sp;
  }
}

// Invert a 128x128 diagonal block of L entirely in LDS.
// Base: 8x 16x16 per-thread-column in registers; then doubling 16->32->64->128
// using the strictly-upper (zero) region of the block as TMP scratch.
__global__ __launch_bounds__(256) void k_diaginv128(const float* __restrict__ L,
                                                    float* __restrict__ W) {
  __shared__ float M[128][128];
  int p = blockIdx.x * 128;
  int tid = threadIdx.x;
  for (int idx = tid; idx < 128 * 32; idx += 256) {
    int r = idx >> 5, c4 = (idx & 31) << 2;
    *reinterpret_cast<float4*>(&M[r][c4]) =
        *reinterpret_cast<const float4*>(&L[(size_t)(p + r) * D + p + c4]);
  }
  __syncthreads();
  // base case: thread t<128 solves column (t&15) of 16x16 sub-block (t>>4)
  float x[16];
  int q = tid >> 4, col = tid & 15;
  if (tid < 128) {
    int b = q << 4;
#pragma unroll
    for (int i = 0; i < 16; ++i) {
      float acc = 0.f;
#pragma unroll
      for (int k = 0; k < i; ++k) acc += M[b + i][b + k] * x[k];
      x[i] = (((i == col) ? 1.f : 0.f) - acc) / M[b + i][b + i];
    }
  }
  __syncthreads();
  if (tid < 128) {
    int b = q << 4;
#pragma unroll
    for (int i = 0; i < 16; ++i) M[b + i][b + col] = x[i];
  }
  __syncthreads();
  // doubling: W_off = -W_C @ (L_B @ W_A); TMP lives in the upper zero block.
  for (int lev = 0; lev < 3; ++lev) {
    int ln = 4 + lev;
    int n = 1 << ln;
    int total = (4 >> lev) << (2 * ln);   // npairs * n * n
    for (int idx = tid; idx < total; idx += 256) {
      int pp = idx >> (2 * ln);
      int rem = idx & ((1 << (2 * ln)) - 1);
      int i = rem >> ln, j = rem & (n - 1);
      int r0 = pp << (ln + 1);
      float acc = 0.f;
      for (int k = j; k < n; ++k) acc += M[r0 + n + i][r0 + k] * M[r0 + k][r0 + j];
      M[r0 + i][r0 + n + j] = acc;       // scratch
    }
    __syncthreads();
    for (int idx = tid; idx < total; idx += 256) {
      int pp = idx >> (2 * ln);
      int rem = idx & ((1 << (2 * ln)) - 1);
      int i = rem >> ln, j = rem & (n - 1);
      int r0 = pp << (ln + 1);
      float acc = 0.f;
      for (int k = 0; k <= i; ++k) acc += M[r0 + n + i][r0 + n + k] * M[r0 + k][r0 + n + j];
      M[r0 + n + i][r0 + j] = -acc;
    }
    __syncthreads();
  }
  // write back, zeroing strict upper (scratch garbage) within the block
  for (int idx = tid; idx < 128 * 32; idx += 256) {
    int r = idx >> 5, c4 = (idx & 31) << 2;
    float4 v = *reinterpret_cast<const float4*>(&M[r][c4]);
    if (c4 + 0 > r) v.x = 0.f;
    if (c4 + 1 > r) v.y = 0.f;
    if (c4 + 2 > r) v.z = 0.f;
    if (c4 + 3 > r) v.w = 0.f;
    *reinterpret_cast<float4*>(&W[(size_t)(p + r) * D + p + c4]) = v;
  }
}

// Batched NN matmul on submatrices: C = alpha * A @ B, all n x n.
__global__ __launch_bounds__(256) void k_nn(const float* __restrict__ A, int lda, int aOff0, int aZ,
                                            const float* __restrict__ B, int ldb, int bOff0, int bZ,
                                            float* __restrict__ C, int ldc, int cOff0, int cZ,
                                            int n, float alpha) {
  __shared__ float As[32][33];
  __shared__ float Bs[32][33];
  const float* Ab = A + aOff0 + (size_t)blockIdx.z * aZ;
  const float* Bb = B + bOff0 + (size_t)blockIdx.z * bZ;
  float* Cb       = C + cOff0 + (size_t)blockIdx.z * cZ;
  int bm = blockIdx.y * 32, bn = blockIdx.x * 32;
  int tid = threadIdx.x;
  int tx = tid & 15, ty = tid >> 4;
  float acc[2][2] = {};
  for (int k0 = 0; k0 < n; k0 += 32) {
    __syncthreads();
    for (int idx = tid; idx < 1024; idx += 256) {
      int r = idx >> 5, c = idx & 31;
      As[r][c] = Ab[(size_t)(bm + r) * lda + k0 + c];
      Bs[r][c] = Bb[(size_t)(k0 + r) * ldb + bn + c];
    }
    __syncthreads();
#pragma unroll
    for (int kk = 0; kk < 32; ++kk) {
      float a0 = As[ty * 2 + 0][kk], a1 = As[ty * 2 + 1][kk];
      float b0 = Bs[kk][tx * 2 + 0], b1 = Bs[kk][tx * 2 + 1];
      acc[0][0] += a0 * b0; acc[0][1] += a0 * b1;
      acc[1][0] += a1 * b0; acc[1][1] += a1 * b1;
    }
  }
#pragma unroll
  for (int i = 0; i < 2; ++i)
#pragma unroll
    for (int j = 0; j < 2; ++j)
      Cb[(size_t)(bm + ty * 2 + i) * ldc + bn + tx * 2 + j] = alpha * acc[i][j];
}

// NT matmul with gathered A: row r reads A0 (r<split) else A1 (r-split).
// btri: B rows lower-triangular -> clip K at bn+64.
// aq (optional): blockIdx.y==0 also writes row sum-of-squares of A rows.
__global__ __launch_bounds__(256) void k_ntg(const float* __restrict__ A0,
                                             const float* __restrict__ A1, int split,
                                             const float* __restrict__ B,
                                             float* __restrict__ Cout,
                                             int M, int N, int K, int btri,
                                             float* __restrict__ aq) {
  __shared__ float As[16][68];
  __shared__ float Bs[16][68];
  int bm = blockIdx.x * 64, bn = blockIdx.y * 64;
  int Klim = btri ? min(K, bn + 64) : K;
  int tid = threadIdx.x;
  int tx = tid & 15, ty = tid >> 4;
  int lrow = tid >> 2;
  int lk4  = (tid & 3) << 2;
  int r = bm + lrow;
  const float* arow = (r < split) ? (A0 + (size_t)r * K) : (A1 + (size_t)(r - split) * K);
  const float* brow = B + (size_t)(bn + lrow) * K;
  float acc[4][4] = {};
  float sq = 0.f;
  bool do_aq = (aq != nullptr) && (blockIdx.y == 0);
  for (int k0 = 0; k0 < Klim; k0 += 16) {
    float4 av = *reinterpret_cast<const float4*>(&arow[k0 + lk4]);
    float4 bv = *reinterpret_cast<const float4*>(&brow[k0 + lk4]);
    if (do_aq) sq += av.x * av.x + av.y * av.y + av.z * av.z + av.w * av.w;
    __syncthreads();
    As[lk4 + 0][lrow] = av.x; As[lk4 + 1][lrow] = av.y;
    As[lk4 + 2][lrow] = av.z; As[lk4 + 3][lrow] = av.w;
    Bs[lk4 + 0][lrow] = bv.x; Bs[lk4 + 1][lrow] = bv.y;
    Bs[lk4 + 2][lrow] = bv.z; Bs[lk4 + 3][lrow] = bv.w;
    __syncthreads();
#pragma unroll
    for (int kk = 0; kk < 16; ++kk) {
      float a0 = As[kk][ty * 4 + 0], a1 = As[kk][ty * 4 + 1];
      float a2 = As[kk][ty * 4 + 2], a3 = As[kk][ty * 4 + 3];
      float b0 = Bs[kk][tx * 4 + 0], b1 = Bs[kk][tx * 4 + 1];
      float b2 = Bs[kk][tx * 4 + 2], b3 = Bs[kk][tx * 4 + 3];
      acc[0][0] += a0 * b0; acc[0][1] += a0 * b1; acc[0][2] += a0 * b2; acc[0][3] += a0 * b3;
      acc[1][0] += a1 * b0; acc[1][1] += a1 * b1; acc[1][2] += a1 * b2; acc[1][3] += a1 * b3;
      acc[2][0] += a2 * b0; acc[2][1] += a2 * b1; acc[2][2] += a2 * b2; acc[2][3] += a2 * b3;
      acc[3][0] += a3 * b0; acc[3][1] += a3 * b1; acc[3][2] += a3 * b2; acc[3][3] += a3 * b3;
    }
  }
  if (do_aq) {
    sq += __shfl_down(sq, 2);
    sq += __shfl_down(sq, 1);
    if ((tid & 3) == 0) aq[r] = sq;
  }
#pragma unroll
  for (int i = 0; i < 4; ++i)
#pragma unroll
    for (int j = 0; j < 4; ++j)
      Cout[(size_t)(bm + ty * 4 + i) * N + bn + tx * 4 + j] = acc[i][j];
}

// per class: stage 7 rows (6 UW + MW) in LDS, 7x7 Gram via 4 waves,
// then 6x6 Cholesky -> Minv, logdetM, bias; sv, h.
__global__ __launch_bounds__(256) void k_msmall(const float* __restrict__ YY,
                                                const float* __restrict__ S,
                                                float* __restrict__ Minv, float* __restrict__ biasv,
                                                float* __restrict__ hbuf, float* __restrict__ svec) {
  __shared__ float4 R4[7 * 128];
  __shared__ float Dsh[49];
  int c = blockIdx.x, tid = threadIdx.x;
  int lane = tid & 63, wave = tid >> 6;
  for (int idx = tid; idx < 7 * 128; idx += 256) {
    int row = idx >> 7, c4 = idx & 127;
    const float* src = (row < 6) ? (YY + (size_t)(c * 6 + row) * D)
                                 : (YY + (size_t)(384 + c) * D);
    R4[row * 128 + c4] = reinterpret_cast<const float4*>(src)[c4];
  }
  __syncthreads();
  const float* R = reinterpret_cast<const float*>(R4);
  const int PI[28] = {0,0,0,0,0,0,0, 1,1,1,1,1,1, 2,2,2,2,2, 3,3,3,3, 4,4,4, 5,5, 6};
  const int PJ[28] = {0,1,2,3,4,5,6, 1,2,3,4,5,6, 2,3,4,5,6, 3,4,5,6, 4,5,6, 5,6, 6};
  for (int p = wave; p < 28; p += 4) {
    int i = PI[p], j = PJ[p];
    float part = 0.f;
#pragma unroll
    for (int it = 0; it < 8; ++it) {
      int d = lane + it * 64;
      part += R[i * D + d] * R[j * D + d];
    }
    part = wred(part);
    if (lane == 0) { Dsh[i * 7 + j] = part; Dsh[j * 7 + i] = part; }
  }
  __syncthreads();
  if (tid == 0) {
    float Mm[6][6], Rc[6][6], Rin[6][6];
    for (int i = 0; i < 6; ++i)
      for (int j = 0; j < 6; ++j) {
        Mm[i][j] = Dsh[i * 7 + j] + (i == j ? 1.f : 0.f);
        Rc[i][j] = 0.f; Rin[i][j] = 0.f;
      }
    float logdetM = 0.f;
    for (int i = 0; i < 6; ++i) {
      float s = Mm[i][i];
      for (int k = 0; k < i; ++k) s -= Rc[i][k] * Rc[i][k];
      float rii = sqrtf(s);
      Rc[i][i] = rii;
      logdetM += logf(rii);
      for (int r = i + 1; r < 6; ++r) {
        float s2 = Mm[r][i];
        for (int k = 0; k < i; ++k) s2 -= Rc[r][k] * Rc[i][k];
        Rc[r][i] = s2 / rii;
      }
    }
    logdetM *= 2.f;
    for (int j = 0; j < 6; ++j) {
      Rin[j][j] = 1.f / Rc[j][j];
      for (int i = j + 1; i < 6; ++i) {
        float s3 = 0.f;
        for (int k = j; k < i; ++k) s3 += Rc[i][k] * Rin[k][j];
        Rin[i][j] = -s3 / Rc[i][i];
      }
    }
    for (int i = 0; i < 6; ++i)
      for (int j = 0; j < 6; ++j) {
        float s4 = 0.f;
        for (int k = 0; k < 6; ++k) s4 += Rin[k][i] * Rin[k][j];
        Minv[c * 36 + i * 6 + j] = s4;
      }
    for (int j = 0; j < 6; ++j) svec[c * 6 + j] = Dsh[j * 7 + 6];
    hbuf[c] = Dsh[48];
    biasv[c] = S[3] - 0.5f * (S[9] + logdetM);
  }
}

__global__ void k_final(const float* __restrict__ aq, const float* __restrict__ T2,
                        const float* __restrict__ hbuf,
                        const float* __restrict__ svec, const float* __restrict__ Minv,
                        const float* __restrict__ biasv, const float* __restrict__ S,
                        float* __restrict__ out) {
  int t = blockIdx.x * blockDim.x + threadIdx.x;
  if (t >= NQ * NC) return;
  int q = t >> 6, c = t & 63;
  const float* t2 = T2 + (size_t)q * NR;
  float e[6];
#pragma unroll
  for (int j = 0; j < 6; ++j) e[j] = t2[c * 6 + j] - svec[c * 6 + j];
  float quad = 0.f;
#pragma unroll
  for (int i = 0; i < 6; ++i) {
    float acc = 0.f;
#pragma unroll
    for (int j = 0; j < 6; ++j) acc += Minv[c * 36 + i * 6 + j] * e[j];
    quad += e[i] * acc;
  }
  float xAmu = t2[384 + c];
  float dist = (aq[q] - 2.f * xAmu + hbuf[c] - quad) * S[8];
  out[t] = biasv[c] - S[10] * log1pf(dist * S[11]);
}

extern "C" void kernel_launch(void* const* d_in, const int* in_sizes, int n_in,
                              void* d_out, int out_size, void* d_ws, size_t ws_size,
                              hipStream_t stream) {
  const float* Xs   = (const float*)d_in[0];
  const float* Xq   = (const float*)d_in[2];
  const float* m    = (const float*)d_in[3];
  const float* kap  = (const float*)d_in[4];
  const float* nu   = (const float*)d_in[5];
  const float* diag = (const float*)d_in[6];
  const float* low  = (const float*)d_in[7];
  float* ws = (float*)d_ws;

  float* S    = ws + OFF_S;
  float* L    = ws + OFF_L;
  float* W    = ws + OFF_W;
  float* TMP  = ws + OFF_TMP;
  float* Ub   = ws + OFF_UB;
  float* YY   = ws + OFF_YY;   // rows 0..447 = UW/MW, rows 448.. = Y
  float* T2   = ws + OFF_T2;
  float* Minv = ws + OFF_MINV;
  float* bias = ws + OFF_BIAS;
  float* hb   = ws + OFF_H;
  float* aq   = ws + OFF_AQ;
  float* sv   = ws + OFF_SV;

  hipLaunchKernelGGL(k_prep, dim3(1089), dim3(256), 0, stream,
                     diag, low, Xs, m, kap, nu, L, W, Ub, S);
  hipLaunchKernelGGL(k_diaginv128, dim3(4), dim3(256), 0, stream, L, W);
  // remaining doubling levels: n = 128, 256
  for (int n = 128; n <= 256; n <<= 1) {
    int np = D / (2 * n);
    int g = n / 32;
    hipLaunchKernelGGL(k_nn, dim3(g, g, np), dim3(256), 0, stream,
                       L, D, n * D, 2 * n * (D + 1),
                       W, D, 0, 2 * n * (D + 1),
                       TMP, n, 0, n * n, n, 1.0f);
    hipLaunchKernelGGL(k_nn, dim3(g, g, np), dim3(256), 0, stream,
                       W, D, n * (D + 1), 2 * n * (D + 1),
                       TMP, n, 0, n * n,
                       W, D, n * D, 2 * n * (D + 1), n, -1.0f);
  }
  // YY = [Ub; Xq] @ W^T  (2496 x 512 x 512, triangular-clipped)
  hipLaunchKernelGGL(k_ntg, dim3(MT / 64, D / 64), dim3(256), 0, stream,
                     Ub, Xq, NR, W, YY, MT, D, D, 1, (float*)nullptr);
  hipLaunchKernelGGL(k_msmall, dim3(NC), dim3(256), 0, stream, YY, S, Minv, bias, hb, sv);
  // T2 = Y @ [UW;MW]^T  (2048 x 448 x 512), fused aq = rowsumsq(Y)
  hipLaunchKernelGGL(k_ntg, dim3(NQ / 64, NR / 64), dim3(256), 0, stream,
                     YY + (size_t)NR * D, YY + (size_t)NR * D, 0, YY, T2, NQ, NR, D, 0, aq);
  hipLaunchKernelGGL(k_final, dim3(NQ * NC / 256), dim3(256), 0, stream,
                     aq, T2, hb, sv, Minv, bias, S, (float*)d_out);
}

// Round 5
// 127.128 us; speedup vs baseline: 1.6292x; 1.6292x over previous
//
#include <hip/hip_runtime.h>
#include <math.h>

#define D 512
#define NC 64
#define NQ 2048
#define NR 448   // 384 U rows + 64 MU rows
#define MT (NR + NQ)   // 2496 combined GEMM rows

// ---- workspace float offsets ----
#define OFF_S    0
#define OFF_L    32
#define OFF_W    (OFF_L + D*D)
#define OFF_TMP  (OFF_W + D*D)          // 256*256 doubling temp
#define OFF_UB   (OFF_TMP + 65536)      // [U(384); MU(64)] : NR x D
#define OFF_YY   (OFF_UB + NR*D)        // [UW(384); MW(64); Y(2048)] : MT x D
#define OFF_T2   (OFF_YY + MT*D)        // NQ x NR
#define OFF_MINV (OFF_T2 + NQ*NR)       // NC*36
#define OFF_BIAS (OFF_MINV + NC*36)
#define OFF_H    (OFF_BIAS + NC)
#define OFF_AQ   (OFF_H + NC)
#define OFF_SV   (OFF_AQ + NQ)          // NC*6

__device__ inline float wred(float v) {
#pragma unroll
  for (int off = 32; off; off >>= 1) v += __shfl_down(v, off);
  return v;  // lane 0 holds sum
}

// Fused prep: blocks 0..1023 build L (+zero W upper), 1024..1087 classprep,
// 1088 computes the shared scalars.
__global__ __launch_bounds__(256) void k_prep(const float* __restrict__ diag,
                                              const float* __restrict__ low,
                                              const float* __restrict__ Xs,
                                              const float* __restrict__ m,
                                              const float* __restrict__ kp,
                                              const float* __restrict__ nup,
                                              float* __restrict__ L, float* __restrict__ W,
                                              float* __restrict__ Ub, float* __restrict__ S) {
  int bid = blockIdx.x, tid = threadIdx.x;
  if (bid < 1024) {
    int t = bid * 256 + tid;
    int i = t / D, j = t % D;
    float v;
    if (i == j)      v = fabsf(diag[i]);
    else if (i > j)  v = low[t];
    else             v = 0.f;
    L[t] = v;
    if (i < j) W[t] = 0.f;
  } else if (bid < 1088) {
    int c = bid - 1024;
    float kappa = kp[0];
    float kn = fabsf(kappa) + 1e-6f + 5.0f;
    float xw = 5.0f / kn;
    float mw = fabsf(kappa + 1e-6f) / kn;
    float sw = sqrtf((fabsf(kappa) + 1e-6f) / kn);
    const float is5 = 0.44721359549995793f;  // 1/sqrt(5)
    for (int d = tid; d < D; d += 256) {
      float x0 = Xs[(size_t)(c * 5 + 0) * D + d];
      float x1 = Xs[(size_t)(c * 5 + 1) * D + d];
      float x2 = Xs[(size_t)(c * 5 + 2) * D + d];
      float x3 = Xs[(size_t)(c * 5 + 3) * D + d];
      float x4 = Xs[(size_t)(c * 5 + 4) * D + d];
      float xm = (x0 + x1 + x2 + x3 + x4) * 0.2f;
      float mv = m[d];
      Ub[(size_t)(c * 6 + 0) * D + d] = x0 * is5;
      Ub[(size_t)(c * 6 + 1) * D + d] = x1 * is5;
      Ub[(size_t)(c * 6 + 2) * D + d] = x2 * is5;
      Ub[(size_t)(c * 6 + 3) * D + d] = x3 * is5;
      Ub[(size_t)(c * 6 + 4) * D + d] = x4 * is5;
      Ub[(size_t)(c * 6 + 5) * D + d] = sw * (xm - mv);
      Ub[(size_t)(384 + c) * D + d]   = mw * mv + xw * xm;
    }
  } else {
    if (tid >= 64) return;
    int lane = tid;
    float part = 0.f;
    for (int i = lane; i < D; i += 64) part += logf(fabsf(diag[i]));
    part = wred(part);
    if (lane != 0) return;
    float lda = 2.f * part;
    float kappa = kp[0], nu = nup[0];
    float kn = fabsf(kappa) + 1e-6f + 5.0f;
    float sp = fmaxf(nu, (float)(D - 1) + 1e-6f) + 5.0f - (float)D + 2.0f;
    float bias_shared = lgammaf(0.5f * (sp + (float)D)) - lgammaf(0.5f * sp)
                      - 0.5f * (float)D * logf(sp);
    float scale = kn * sp / (kn + 1.0f);
    S[0] = kn; S[1] = sp; S[2] = scale; S[3] = bias_shared;
    S[8] = 1.f / scale;
    S[9] = (float)D * logf(scale) + lda;
    S[10] = 0.5f * (sp + (float)D);
    S[11] = 1.f / sp;
  }
}

#define MPAD 130

// In-LDS micro-tiled GEMM: C[cr..][cc..] = (+/-) A[ar..][ac..] @ B[br..][bc..],
// all N x N sub-blocks of M. 256 threads, (N/16)^2 outputs per thread,
// fully unrolled fixed-bound k-loop -> pipelined LDS reads.
template <int N>
__device__ inline void lds_mm(float (*M)[MPAD], int ar, int ac, int br, int bc,
                              int cr, int cc, bool neg) {
  const int T = N / 16;
  int tx = (threadIdx.x & 15) * T, ty = (threadIdx.x >> 4) * T;
  float acc[T][T];
#pragma unroll
  for (int i = 0; i < T; ++i)
#pragma unroll
    for (int j = 0; j < T; ++j) acc[i][j] = 0.f;
#pragma unroll 8
  for (int k = 0; k < N; ++k) {
    float a[T], b[T];
#pragma unroll
    for (int i = 0; i < T; ++i) a[i] = M[ar + ty + i][ac + k];
#pragma unroll
    for (int j = 0; j < T; ++j) b[j] = M[br + k][bc + tx + j];
#pragma unroll
    for (int i = 0; i < T; ++i)
#pragma unroll
      for (int j = 0; j < T; ++j) acc[i][j] += a[i] * b[j];
  }
#pragma unroll
  for (int i = 0; i < T; ++i)
#pragma unroll
    for (int j = 0; j < T; ++j)
      M[cr + ty + i][cc + tx + j] = neg ? -acc[i][j] : acc[i][j];
}

// Invert a 128x128 diagonal block of L entirely in LDS.
// Base: 16x16 per-thread-column in registers; doubling 16->32->64->128 via
// micro-tiled LDS GEMMs, scratch in the strictly-upper (zero) region.
__global__ __launch_bounds__(256) void k_inv128(const float* __restrict__ L,
                                                float* __restrict__ W) {
  __shared__ float M[128][MPAD];
  int p = blockIdx.x * 128;
  int tid = threadIdx.x;
  for (int idx = tid; idx < 128 * 32; idx += 256) {
    int r = idx >> 5, c4 = (idx & 31) << 2;
    *reinterpret_cast<float4*>(&M[r][c4]) =
        *reinterpret_cast<const float4*>(&L[(size_t)(p + r) * D + p + c4]);
  }
  __syncthreads();
  // base: thread t<128 solves column (t&15) of 16x16 diag sub-block (t>>4)
  {
    float x[16];
    int q = tid >> 4, col = tid & 15;
    if (tid < 128) {
      int b = q << 4;
#pragma unroll
      for (int i = 0; i < 16; ++i) {
        float acc = 0.f;
#pragma unroll
        for (int k = 0; k < i; ++k) acc += M[b + i][b + k] * x[k];
        x[i] = (((i == col) ? 1.f : 0.f) - acc) / M[b + i][b + i];
      }
    }
    __syncthreads();
    if (tid < 128) {
      int b = q << 4;
#pragma unroll
      for (int i = 0; i < 16; ++i) M[b + i][b + col] = x[i];
    }
    __syncthreads();
  }
  // doubling levels: W_off = -C_inv @ (L_B @ A_inv)
#define LEVEL(n)                                                         \
  for (int pp = 0; pp < 128 / (2 * n); ++pp) {                           \
    int r0 = 2 * n * pp;                                                 \
    lds_mm<n>(M, r0 + n, r0, r0, r0, r0, r0 + n, false);                 \
  }                                                                      \
  __syncthreads();                                                       \
  for (int pp = 0; pp < 128 / (2 * n); ++pp) {                           \
    int r0 = 2 * n * pp;                                                 \
    lds_mm<n>(M, r0 + n, r0 + n, r0, r0 + n, r0 + n, r0, true);          \
  }                                                                      \
  __syncthreads();
  LEVEL(16)
  LEVEL(32)
  LEVEL(64)
#undef LEVEL
  // write back, zeroing strict upper (scratch garbage) within the block
  for (int idx = tid; idx < 128 * 32; idx += 256) {
    int r = idx >> 5, c4 = (idx & 31) << 2;
    float4 v = *reinterpret_cast<const float4*>(&M[r][c4]);
    if (c4 + 0 > r) v.x = 0.f;
    if (c4 + 1 > r) v.y = 0.f;
    if (c4 + 2 > r) v.z = 0.f;
    if (c4 + 3 > r) v.w = 0.f;
    *reinterpret_cast<float4*>(&W[(size_t)(p + r) * D + p + c4]) = v;
  }
}

// Batched NN matmul on submatrices: C = alpha * A @ B, all n x n.
__global__ __launch_bounds__(256) void k_nn(const float* __restrict__ A, int lda, int aOff0, int aZ,
                                            const float* __restrict__ B, int ldb, int bOff0, int bZ,
                                            float* __restrict__ C, int ldc, int cOff0, int cZ,
                                            int n, float alpha) {
  __shared__ float As[32][33];
  __shared__ float Bs[32][33];
  const float* Ab = A + aOff0 + (size_t)blockIdx.z * aZ;
  const float* Bb = B + bOff0 + (size_t)blockIdx.z * bZ;
  float* Cb       = C + cOff0 + (size_t)blockIdx.z * cZ;
  int bm = blockIdx.y * 32, bn = blockIdx.x * 32;
  int tid = threadIdx.x;
  int tx = tid & 15, ty = tid >> 4;
  float acc[2][2] = {};
  for (int k0 = 0; k0 < n; k0 += 32) {
    __syncthreads();
    for (int idx = tid; idx < 1024; idx += 256) {
      int r = idx >> 5, c = idx & 31;
      As[r][c] = Ab[(size_t)(bm + r) * lda + k0 + c];
      Bs[r][c] = Bb[(size_t)(k0 + r) * ldb + bn + c];
    }
    __syncthreads();
#pragma unroll
    for (int kk = 0; kk < 32; ++kk) {
      float a0 = As[ty * 2 + 0][kk], a1 = As[ty * 2 + 1][kk];
      float b0 = Bs[kk][tx * 2 + 0], b1 = Bs[kk][tx * 2 + 1];
      acc[0][0] += a0 * b0; acc[0][1] += a0 * b1;
      acc[1][0] += a1 * b0; acc[1][1] += a1 * b1;
    }
  }
#pragma unroll
  for (int i = 0; i < 2; ++i)
#pragma unroll
    for (int j = 0; j < 2; ++j)
      Cb[(size_t)(bm + ty * 2 + i) * ldc + bn + tx * 2 + j] = alpha * acc[i][j];
}

// NT matmul with gathered A: row r reads A0 (r<split) else A1 (r-split).
// btri: B rows lower-triangular -> clip K at bn+64.
// aq (optional): blockIdx.y==0 also writes row sum-of-squares of A rows.
__global__ __launch_bounds__(256) void k_ntg(const float* __restrict__ A0,
                                             const float* __restrict__ A1, int split,
                                             const float* __restrict__ B,
                                             float* __restrict__ Cout,
                                             int M, int N, int K, int btri,
                                             float* __restrict__ aq) {
  __shared__ float As[16][68];
  __shared__ float Bs[16][68];
  int bm = blockIdx.x * 64, bn = blockIdx.y * 64;
  int Klim = btri ? min(K, bn + 64) : K;
  int tid = threadIdx.x;
  int tx = tid & 15, ty = tid >> 4;
  int lrow = tid >> 2;
  int lk4  = (tid & 3) << 2;
  int r = bm + lrow;
  const float* arow = (r < split) ? (A0 + (size_t)r * K) : (A1 + (size_t)(r - split) * K);
  const float* brow = B + (size_t)(bn + lrow) * K;
  float acc[4][4] = {};
  float sq = 0.f;
  bool do_aq = (aq != nullptr) && (blockIdx.y == 0);
  for (int k0 = 0; k0 < Klim; k0 += 16) {
    float4 av = *reinterpret_cast<const float4*>(&arow[k0 + lk4]);
    float4 bv = *reinterpret_cast<const float4*>(&brow[k0 + lk4]);
    if (do_aq) sq += av.x * av.x + av.y * av.y + av.z * av.z + av.w * av.w;
    __syncthreads();
    As[lk4 + 0][lrow] = av.x; As[lk4 + 1][lrow] = av.y;
    As[lk4 + 2][lrow] = av.z; As[lk4 + 3][lrow] = av.w;
    Bs[lk4 + 0][lrow] = bv.x; Bs[lk4 + 1][lrow] = bv.y;
    Bs[lk4 + 2][lrow] = bv.z; Bs[lk4 + 3][lrow] = bv.w;
    __syncthreads();
#pragma unroll
    for (int kk = 0; kk < 16; ++kk) {
      float a0 = As[kk][ty * 4 + 0], a1 = As[kk][ty * 4 + 1];
      float a2 = As[kk][ty * 4 + 2], a3 = As[kk][ty * 4 + 3];
      float b0 = Bs[kk][tx * 4 + 0], b1 = Bs[kk][tx * 4 + 1];
      float b2 = Bs[kk][tx * 4 + 2], b3 = Bs[kk][tx * 4 + 3];
      acc[0][0] += a0 * b0; acc[0][1] += a0 * b1; acc[0][2] += a0 * b2; acc[0][3] += a0 * b3;
      acc[1][0] += a1 * b0; acc[1][1] += a1 * b1; acc[1][2] += a1 * b2; acc[1][3] += a1 * b3;
      acc[2][0] += a2 * b0; acc[2][1] += a2 * b1; acc[2][2] += a2 * b2; acc[2][3] += a2 * b3;
      acc[3][0] += a3 * b0; acc[3][1] += a3 * b1; acc[3][2] += a3 * b2; acc[3][3] += a3 * b3;
    }
  }
  if (do_aq) {
    sq += __shfl_down(sq, 2);
    sq += __shfl_down(sq, 1);
    if ((tid & 3) == 0) aq[r] = sq;
  }
#pragma unroll
  for (int i = 0; i < 4; ++i)
#pragma unroll
    for (int j = 0; j < 4; ++j)
      Cout[(size_t)(bm + ty * 4 + i) * N + bn + tx * 4 + j] = acc[i][j];
}

// per class: stage 7 rows (6 UW + MW) in LDS, 7x7 Gram via 4 waves,
// then 6x6 Cholesky -> Minv, logdetM, bias; sv, h.
__global__ __launch_bounds__(256) void k_msmall(const float* __restrict__ YY,
                                                const float* __restrict__ S,
                                                float* __restrict__ Minv, float* __restrict__ biasv,
                                                float* __restrict__ hbuf, float* __restrict__ svec) {
  __shared__ float4 R4[7 * 128];
  __shared__ float Dsh[49];
  int c = blockIdx.x, tid = threadIdx.x;
  int lane = tid & 63, wave = tid >> 6;
  for (int idx = tid; idx < 7 * 128; idx += 256) {
    int row = idx >> 7, c4 = idx & 127;
    const float* src = (row < 6) ? (YY + (size_t)(c * 6 + row) * D)
                                 : (YY + (size_t)(384 + c) * D);
    R4[row * 128 + c4] = reinterpret_cast<const float4*>(src)[c4];
  }
  __syncthreads();
  const float* R = reinterpret_cast<const float*>(R4);
  const int PI[28] = {0,0,0,0,0,0,0, 1,1,1,1,1,1, 2,2,2,2,2, 3,3,3,3, 4,4,4, 5,5, 6};
  const int PJ[28] = {0,1,2,3,4,5,6, 1,2,3,4,5,6, 2,3,4,5,6, 3,4,5,6, 4,5,6, 5,6, 6};
  for (int p = wave; p < 28; p += 4) {
    int i = PI[p], j = PJ[p];
    float part = 0.f;
#pragma unroll
    for (int it = 0; it < 8; ++it) {
      int d = lane + it * 64;
      part += R[i * D + d] * R[j * D + d];
    }
    part = wred(part);
    if (lane == 0) { Dsh[i * 7 + j] = part; Dsh[j * 7 + i] = part; }
  }
  __syncthreads();
  if (tid == 0) {
    float Mm[6][6], Rc[6][6], Rin[6][6];
    for (int i = 0; i < 6; ++i)
      for (int j = 0; j < 6; ++j) {
        Mm[i][j] = Dsh[i * 7 + j] + (i == j ? 1.f : 0.f);
        Rc[i][j] = 0.f; Rin[i][j] = 0.f;
      }
    float logdetM = 0.f;
    for (int i = 0; i < 6; ++i) {
      float s = Mm[i][i];
      for (int k = 0; k < i; ++k) s -= Rc[i][k] * Rc[i][k];
      float rii = sqrtf(s);
      Rc[i][i] = rii;
      logdetM += logf(rii);
      for (int r = i + 1; r < 6; ++r) {
        float s2 = Mm[r][i];
        for (int k = 0; k < i; ++k) s2 -= Rc[r][k] * Rc[i][k];
        Rc[r][i] = s2 / rii;
      }
    }
    logdetM *= 2.f;
    for (int j = 0; j < 6; ++j) {
      Rin[j][j] = 1.f / Rc[j][j];
      for (int i = j + 1; i < 6; ++i) {
        float s3 = 0.f;
        for (int k = j; k < i; ++k) s3 += Rc[i][k] * Rin[k][j];
        Rin[i][j] = -s3 / Rc[i][i];
      }
    }
    for (int i = 0; i < 6; ++i)
      for (int j = 0; j < 6; ++j) {
        float s4 = 0.f;
        for (int k = 0; k < 6; ++k) s4 += Rin[k][i] * Rin[k][j];
        Minv[c * 36 + i * 6 + j] = s4;
      }
    for (int j = 0; j < 6; ++j) svec[c * 6 + j] = Dsh[j * 7 + 6];
    hbuf[c] = Dsh[48];
    biasv[c] = S[3] - 0.5f * (S[9] + logdetM);
  }
}

__global__ void k_final(const float* __restrict__ aq, const float* __restrict__ T2,
                        const float* __restrict__ hbuf,
                        const float* __restrict__ svec, const float* __restrict__ Minv,
                        const float* __restrict__ biasv, const float* __restrict__ S,
                        float* __restrict__ out) {
  int t = blockIdx.x * blockDim.x + threadIdx.x;
  if (t >= NQ * NC) return;
  int q = t >> 6, c = t & 63;
  const float* t2 = T2 + (size_t)q * NR;
  float e[6];
#pragma unroll
  for (int j = 0; j < 6; ++j) e[j] = t2[c * 6 + j] - svec[c * 6 + j];
  float quad = 0.f;
#pragma unroll
  for (int i = 0; i < 6; ++i) {
    float acc = 0.f;
#pragma unroll
    for (int j = 0; j < 6; ++j) acc += Minv[c * 36 + i * 6 + j] * e[j];
    quad += e[i] * acc;
  }
  float xAmu = t2[384 + c];
  float dist = (aq[q] - 2.f * xAmu + hbuf[c] - quad) * S[8];
  out[t] = biasv[c] - S[10] * log1pf(dist * S[11]);
}

extern "C" void kernel_launch(void* const* d_in, const int* in_sizes, int n_in,
                              void* d_out, int out_size, void* d_ws, size_t ws_size,
                              hipStream_t stream) {
  const float* Xs   = (const float*)d_in[0];
  const float* Xq   = (const float*)d_in[2];
  const float* m    = (const float*)d_in[3];
  const float* kap  = (const float*)d_in[4];
  const float* nu   = (const float*)d_in[5];
  const float* diag = (const float*)d_in[6];
  const float* low  = (const float*)d_in[7];
  float* ws = (float*)d_ws;

  float* S    = ws + OFF_S;
  float* L    = ws + OFF_L;
  float* W    = ws + OFF_W;
  float* TMP  = ws + OFF_TMP;
  float* Ub   = ws + OFF_UB;
  float* YY   = ws + OFF_YY;   // rows 0..447 = UW/MW, rows 448.. = Y
  float* T2   = ws + OFF_T2;
  float* Minv = ws + OFF_MINV;
  float* bias = ws + OFF_BIAS;
  float* hb   = ws + OFF_H;
  float* aq   = ws + OFF_AQ;
  float* sv   = ws + OFF_SV;

  hipLaunchKernelGGL(k_prep, dim3(1089), dim3(256), 0, stream,
                     diag, low, Xs, m, kap, nu, L, W, Ub, S);
  hipLaunchKernelGGL(k_inv128, dim3(4), dim3(256), 0, stream, L, W);
  // remaining doubling level: n = 256
  {
    int n = 256, g = n / 32;
    hipLaunchKernelGGL(k_nn, dim3(g, g, 1), dim3(256), 0, stream,
                       L, D, n * D, 0,
                       W, D, 0, 0,
                       TMP, n, 0, 0, n, 1.0f);
    hipLaunchKernelGGL(k_nn, dim3(g, g, 1), dim3(256), 0, stream,
                       W, D, n * (D + 1), 0,
                       TMP, n, 0, 0,
                       W, D, n * D, 0, n, -1.0f);
  }
  // YY = [Ub; Xq] @ W^T  (2496 x 512 x 512, triangular-clipped)
  hipLaunchKernelGGL(k_ntg, dim3(MT / 64, D / 64), dim3(256), 0, stream,
                     Ub, Xq, NR, W, YY, MT, D, D, 1, (float*)nullptr);
  hipLaunchKernelGGL(k_msmall, dim3(NC), dim3(256), 0, stream, YY, S, Minv, bias, hb, sv);
  // T2 = Y @ [UW;MW]^T  (2048 x 448 x 512), fused aq = rowsumsq(Y)
  hipLaunchKernelGGL(k_ntg, dim3(NQ / 64, NR / 64), dim3(256), 0, stream,
                     YY + (size_t)NR * D, YY + (size_t)NR * D, 0, YY, T2, NQ, NR, D, 0, aq);
  hipLaunchKernelGGL(k_final, dim3(NQ * NC / 256), dim3(256), 0, stream,
                     aq, T2, hb, sv, Minv, bias, S, (float*)d_out);
}

// Round 6
// 115.090 us; speedup vs baseline: 1.7996x; 1.1046x over previous
//
#include <hip/hip_runtime.h>
#include <math.h>

#define D 512
#define NC 64
#define NQ 2048

// ---- workspace float offsets ----
#define OFF_S    0
#define OFF_L    32
#define OFF_W    (OFF_L + D*D)
#define OFF_TMP  (OFF_W + D*D)          // 256*256 doubling temp
#define OFF_UB   (OFF_TMP + 65536)      // Ubp: 512 x D (8 rows/class: 5 shots, dm, MU, 0)
#define OFF_YY   (OFF_UB + 512*D)       // [UWp(512); Y(2048)] : 2560 x D
#define OFF_MINV (OFF_YY + 2560*D)      // NC*36
#define OFF_BIAS (OFF_MINV + NC*36)
#define OFF_H    (OFF_BIAS + NC)
#define OFF_SV   (OFF_H + NC)           // NC*6

__device__ inline float wred(float v) {
#pragma unroll
  for (int off = 32; off; off >>= 1) v += __shfl_down(v, off);
  return v;
}

// Fused prep: blocks 0..1023 build L (+zero W upper), 1024..1087 classprep,
// 1088 computes shared scalars.
__global__ __launch_bounds__(256) void k_prep(const float* __restrict__ diag,
                                              const float* __restrict__ low,
                                              const float* __restrict__ Xs,
                                              const float* __restrict__ m,
                                              const float* __restrict__ kp,
                                              const float* __restrict__ nup,
                                              float* __restrict__ L, float* __restrict__ W,
                                              float* __restrict__ Ub, float* __restrict__ S) {
  int bid = blockIdx.x, tid = threadIdx.x;
  if (bid < 1024) {
    int t = bid * 256 + tid;
    int i = t / D, j = t % D;
    float v;
    if (i == j)      v = fabsf(diag[i]);
    else if (i > j)  v = low[t];
    else             v = 0.f;
    L[t] = v;
    if (i < j) W[t] = 0.f;
  } else if (bid < 1088) {
    int c = bid - 1024;
    float kappa = kp[0];
    float kn = fabsf(kappa) + 1e-6f + 5.0f;
    float xw = 5.0f / kn;
    float mw = fabsf(kappa + 1e-6f) / kn;
    float sw = sqrtf((fabsf(kappa) + 1e-6f) / kn);
    const float is5 = 0.44721359549995793f;  // 1/sqrt(5)
    for (int d = tid; d < D; d += 256) {
      float x0 = Xs[(size_t)(c * 5 + 0) * D + d];
      float x1 = Xs[(size_t)(c * 5 + 1) * D + d];
      float x2 = Xs[(size_t)(c * 5 + 2) * D + d];
      float x3 = Xs[(size_t)(c * 5 + 3) * D + d];
      float x4 = Xs[(size_t)(c * 5 + 4) * D + d];
      float xm = (x0 + x1 + x2 + x3 + x4) * 0.2f;
      float mv = m[d];
      Ub[(size_t)(c * 8 + 0) * D + d] = x0 * is5;
      Ub[(size_t)(c * 8 + 1) * D + d] = x1 * is5;
      Ub[(size_t)(c * 8 + 2) * D + d] = x2 * is5;
      Ub[(size_t)(c * 8 + 3) * D + d] = x3 * is5;
      Ub[(size_t)(c * 8 + 4) * D + d] = x4 * is5;
      Ub[(size_t)(c * 8 + 5) * D + d] = sw * (xm - mv);
      Ub[(size_t)(c * 8 + 6) * D + d] = mw * mv + xw * xm;
      Ub[(size_t)(c * 8 + 7) * D + d] = 0.f;
    }
  } else {
    if (tid >= 64) return;
    int lane = tid;
    float part = 0.f;
    for (int i = lane; i < D; i += 64) part += logf(fabsf(diag[i]));
    part = wred(part);
    if (lane != 0) return;
    float lda = 2.f * part;
    float kappa = kp[0], nu = nup[0];
    float kn = fabsf(kappa) + 1e-6f + 5.0f;
    float sp = fmaxf(nu, (float)(D - 1) + 1e-6f) + 5.0f - (float)D + 2.0f;
    float bias_shared = lgammaf(0.5f * (sp + (float)D)) - lgammaf(0.5f * sp)
                      - 0.5f * (float)D * logf(sp);
    float scale = kn * sp / (kn + 1.0f);
    S[0] = kn; S[1] = sp; S[2] = scale; S[3] = bias_shared;
    S[8] = 1.f / scale;
    S[9] = (float)D * logf(scale) + lda;
    S[10] = 0.5f * (sp + (float)D);
    S[11] = 1.f / sp;
  }
}

#define MPAD 130

template <int N>
__device__ inline void lds_mm(float (*M)[MPAD], int ar, int ac, int br, int bc,
                              int cr, int cc, bool neg) {
  const int T = N / 16;
  int tx = (threadIdx.x & 15) * T, ty = (threadIdx.x >> 4) * T;
  float acc[T][T];
#pragma unroll
  for (int i = 0; i < T; ++i)
#pragma unroll
    for (int j = 0; j < T; ++j) acc[i][j] = 0.f;
#pragma unroll 8
  for (int k = 0; k < N; ++k) {
    float a[T], b[T];
#pragma unroll
    for (int i = 0; i < T; ++i) a[i] = M[ar + ty + i][ac + k];
#pragma unroll
    for (int j = 0; j < T; ++j) b[j] = M[br + k][bc + tx + j];
#pragma unroll
    for (int i = 0; i < T; ++i)
#pragma unroll
      for (int j = 0; j < T; ++j) acc[i][j] += a[i] * b[j];
  }
#pragma unroll
  for (int i = 0; i < T; ++i)
#pragma unroll
    for (int j = 0; j < T; ++j)
      M[cr + ty + i][cc + tx + j] = neg ? -acc[i][j] : acc[i][j];
}

// Invert a 128x128 diagonal block of L entirely in LDS.
__global__ __launch_bounds__(256) void k_inv128(const float* __restrict__ L,
                                                float* __restrict__ W) {
  __shared__ float M[128][MPAD];
  int p = blockIdx.x * 128;
  int tid = threadIdx.x;
  for (int idx = tid; idx < 128 * 32; idx += 256) {
    int r = idx >> 5, c4 = (idx & 31) << 2;
    *reinterpret_cast<float4*>(&M[r][c4]) =
        *reinterpret_cast<const float4*>(&L[(size_t)(p + r) * D + p + c4]);
  }
  __syncthreads();
  {
    float x[16];
    int q = tid >> 4, col = tid & 15;
    if (tid < 128) {
      int b = q << 4;
#pragma unroll
      for (int i = 0; i < 16; ++i) {
        float acc = 0.f;
#pragma unroll
        for (int k = 0; k < i; ++k) acc += M[b + i][b + k] * x[k];
        x[i] = (((i == col) ? 1.f : 0.f) - acc) / M[b + i][b + i];
      }
    }
    __syncthreads();
    if (tid < 128) {
      int b = q << 4;
#pragma unroll
      for (int i = 0; i < 16; ++i) M[b + i][b + col] = x[i];
    }
    __syncthreads();
  }
#define LEVEL(n)                                                         \
  for (int pp = 0; pp < 128 / (2 * n); ++pp) {                           \
    int r0 = 2 * n * pp;                                                 \
    lds_mm<n>(M, r0 + n, r0, r0, r0, r0, r0 + n, false);                 \
  }                                                                      \
  __syncthreads();                                                       \
  for (int pp = 0; pp < 128 / (2 * n); ++pp) {                           \
    int r0 = 2 * n * pp;                                                 \
    lds_mm<n>(M, r0 + n, r0 + n, r0, r0 + n, r0 + n, r0, true);          \
  }                                                                      \
  __syncthreads();
  LEVEL(16)
  LEVEL(32)
  LEVEL(64)
#undef LEVEL
  for (int idx = tid; idx < 128 * 32; idx += 256) {
    int r = idx >> 5, c4 = (idx & 31) << 2;
    float4 v = *reinterpret_cast<const float4*>(&M[r][c4]);
    if (c4 + 0 > r) v.x = 0.f;
    if (c4 + 1 > r) v.y = 0.f;
    if (c4 + 2 > r) v.z = 0.f;
    if (c4 + 3 > r) v.w = 0.f;
    *reinterpret_cast<float4*>(&W[(size_t)(p + r) * D + p + c4]) = v;
  }
}

// Batched NN matmul on submatrices (used for the n=256 doubling level).
__global__ __launch_bounds__(256) void k_nn(const float* __restrict__ A, int lda, int aOff0,
                                            const float* __restrict__ B, int ldb, int bOff0,
                                            float* __restrict__ C, int ldc, int cOff0,
                                            int n, float alpha) {
  __shared__ float As[32][33];
  __shared__ float Bs[32][33];
  const float* Ab = A + aOff0;
  const float* Bb = B + bOff0;
  float* Cb       = C + cOff0;
  int bm = blockIdx.y * 32, bn = blockIdx.x * 32;
  int tid = threadIdx.x;
  int tx = tid & 15, ty = tid >> 4;
  float acc[2][2] = {};
  for (int k0 = 0; k0 < n; k0 += 32) {
    __syncthreads();
    for (int idx = tid; idx < 1024; idx += 256) {
      int r = idx >> 5, c = idx & 31;
      As[r][c] = Ab[(size_t)(bm + r) * lda + k0 + c];
      Bs[r][c] = Bb[(size_t)(k0 + r) * ldb + bn + c];
    }
    __syncthreads();
#pragma unroll
    for (int kk = 0; kk < 32; ++kk) {
      float a0 = As[ty * 2 + 0][kk], a1 = As[ty * 2 + 1][kk];
      float b0 = Bs[kk][tx * 2 + 0], b1 = Bs[kk][tx * 2 + 1];
      acc[0][0] += a0 * b0; acc[0][1] += a0 * b1;
      acc[1][0] += a1 * b0; acc[1][1] += a1 * b1;
    }
  }
#pragma unroll
  for (int i = 0; i < 2; ++i)
#pragma unroll
    for (int j = 0; j < 2; ++j)
      Cb[(size_t)(bm + ty * 2 + i) * ldc + bn + tx * 2 + j] = alpha * acc[i][j];
}

// Big NT GEMM: 64x64 tile per block, 4 waves splitting K (equal trip counts),
// per-wave private LDS staging, 8x8 micro with ds_read_b128, 4-phase LDS merge.
// EPI=0: plain write to Cout (ldc). EPI=1: fused MetaQDA epilogue -> outp.
// btri: B rows lower-triangular -> Klim = bn+64.
template <int EPI>
__global__ __launch_bounds__(256) void k_big(
    const float* __restrict__ A0, const float* __restrict__ A1, int split,
    const float* __restrict__ B, float* __restrict__ Cout, int ldc,
    int Ktot, int btri,
    const float* __restrict__ sv, const float* __restrict__ Minv,
    const float* __restrict__ biasv, const float* __restrict__ hb,
    const float* __restrict__ S, float* __restrict__ outp) {
  __shared__ float As[4][16][68];
  __shared__ float Bs[4][16][68];
  __shared__ float accb[64][68];
  __shared__ float aqs[4][64];
  int tid = threadIdx.x;
  int w = tid >> 6, lane = tid & 63;
  int ly = lane >> 3, lx = lane & 7;
  int bm = blockIdx.x * 64, bn = blockIdx.y * 64;
  int Klim = btri ? (bn + 64) : Ktot;
  int chunk = Klim >> 2;                 // multiple of 16
  int k0beg = w * chunk, k0end = k0beg + chunk;
  int r = bm + lane;
  const float* arow = (r < split) ? (A0 + (size_t)r * Ktot)
                                  : (A1 + (size_t)(r - split) * Ktot);
  const float* brow = B + (size_t)(bn + lane) * Ktot;
  float acc[8][8];
#pragma unroll
  for (int i = 0; i < 8; ++i)
#pragma unroll
    for (int j = 0; j < 8; ++j) acc[i][j] = 0.f;
  float sq = 0.f;
  for (int k0 = k0beg; k0 < k0end; k0 += 16) {
    float4 av[4], bv[4];
#pragma unroll
    for (int i = 0; i < 4; ++i) {
      av[i] = *reinterpret_cast<const float4*>(&arow[k0 + i * 4]);
      bv[i] = *reinterpret_cast<const float4*>(&brow[k0 + i * 4]);
    }
    if (EPI) {
#pragma unroll
      for (int i = 0; i < 4; ++i)
        sq += av[i].x * av[i].x + av[i].y * av[i].y + av[i].z * av[i].z + av[i].w * av[i].w;
    }
    // drain this wave's pending ds_reads before overwriting its buffers
    asm volatile("s_waitcnt lgkmcnt(0)" ::: "memory");
#pragma unroll
    for (int i = 0; i < 4; ++i) {
      As[w][i * 4 + 0][lane] = av[i].x; As[w][i * 4 + 1][lane] = av[i].y;
      As[w][i * 4 + 2][lane] = av[i].z; As[w][i * 4 + 3][lane] = av[i].w;
      Bs[w][i * 4 + 0][lane] = bv[i].x; Bs[w][i * 4 + 1][lane] = bv[i].y;
      Bs[w][i * 4 + 2][lane] = bv[i].z; Bs[w][i * 4 + 3][lane] = bv[i].w;
    }
    // drain writes before cross-lane reads (same wave, lockstep)
    asm volatile("s_waitcnt lgkmcnt(0)" ::: "memory");
#pragma unroll
    for (int kk = 0; kk < 16; ++kk) {
      float4 a0 = *reinterpret_cast<const float4*>(&As[w][kk][ly * 8]);
      float4 a1 = *reinterpret_cast<const float4*>(&As[w][kk][ly * 8 + 4]);
      float4 b0 = *reinterpret_cast<const float4*>(&Bs[w][kk][lx * 8]);
      float4 b1 = *reinterpret_cast<const float4*>(&Bs[w][kk][lx * 8 + 4]);
      float a[8] = {a0.x, a0.y, a0.z, a0.w, a1.x, a1.y, a1.z, a1.w};
      float bb[8] = {b0.x, b0.y, b0.z, b0.w, b1.x, b1.y, b1.z, b1.w};
#pragma unroll
      for (int i = 0; i < 8; ++i)
#pragma unroll
        for (int j = 0; j < 8; ++j) acc[i][j] += a[i] * bb[j];
    }
  }
  if (EPI) aqs[w][lane] = sq;
  __syncthreads();
  // 4-phase merge of the 4 waves' partial accs into accb
#pragma unroll
  for (int ph = 0; ph < 4; ++ph) {
    int q = (w + ph) & 3;
    if ((ly >> 1) == q) {
#pragma unroll
      for (int i = 0; i < 8; ++i) {
        float* dst = &accb[ly * 8 + i][lx * 8];
        if (ph == 0) {
#pragma unroll
          for (int j = 0; j < 8; ++j) dst[j] = acc[i][j];
        } else {
#pragma unroll
          for (int j = 0; j < 8; ++j) dst[j] += acc[i][j];
        }
      }
    }
    __syncthreads();
  }
  int rr = tid & 63, g = tid >> 6;
  if (EPI == 0) {
#pragma unroll
    for (int j = 0; j < 16; j += 4)
      *reinterpret_cast<float4*>(&Cout[(size_t)(bm + rr) * ldc + bn + g * 16 + j]) =
          *reinterpret_cast<const float4*>(&accb[rr][g * 16 + j]);
  } else {
    float aq = aqs[0][rr] + aqs[1][rr] + aqs[2][rr] + aqs[3][rr];
    float s8 = S[8], s10 = S[10], s11 = S[11];
#pragma unroll
    for (int cc = 0; cc < 2; ++cc) {
      int clc = g * 2 + cc;          // class within tile (0..7)
      int c = (bn >> 3) + clc;       // global class
      const float* t = &accb[rr][clc * 8];
      float e[6];
#pragma unroll
      for (int j = 0; j < 6; ++j) e[j] = t[j] - sv[c * 6 + j];
      float quad = 0.f;
#pragma unroll
      for (int i = 0; i < 6; ++i) {
        float a = 0.f;
#pragma unroll
        for (int j = 0; j < 6; ++j) a += Minv[c * 36 + i * 6 + j] * e[j];
        quad += e[i] * a;
      }
      float dist = (aq - 2.f * t[6] + hb[c] - quad) * s8;
      outp[(size_t)(bm + rr) * NC + c] = biasv[c] - s10 * log1pf(dist * s11);
    }
  }
}

// per class: stage 7 contiguous rows (6 UW + MW) in LDS, 7x7 Gram via 4 waves,
// then 6x6 Cholesky -> Minv, logdetM, bias; sv, h.
__global__ __launch_bounds__(256) void k_msmall(const float* __restrict__ YY,
                                                const float* __restrict__ S,
                                                float* __restrict__ Minv, float* __restrict__ biasv,
                                                float* __restrict__ hbuf, float* __restrict__ svec) {
  __shared__ float4 R4[7 * 128];
  __shared__ float Dsh[49];
  int c = blockIdx.x, tid = threadIdx.x;
  int lane = tid & 63, wave = tid >> 6;
  const float4* src = reinterpret_cast<const float4*>(YY + (size_t)c * 8 * D);
  for (int idx = tid; idx < 7 * 128; idx += 256) R4[idx] = src[idx];
  __syncthreads();
  const float* R = reinterpret_cast<const float*>(R4);
  const int PI[28] = {0,0,0,0,0,0,0, 1,1,1,1,1,1, 2,2,2,2,2, 3,3,3,3, 4,4,4, 5,5, 6};
  const int PJ[28] = {0,1,2,3,4,5,6, 1,2,3,4,5,6, 2,3,4,5,6, 3,4,5,6, 4,5,6, 5,6, 6};
  for (int p = wave; p < 28; p += 4) {
    int i = PI[p], j = PJ[p];
    float part = 0.f;
#pragma unroll
    for (int it = 0; it < 8; ++it) {
      int d = lane + it * 64;
      part += R[i * D + d] * R[j * D + d];
    }
    part = wred(part);
    if (lane == 0) { Dsh[i * 7 + j] = part; Dsh[j * 7 + i] = part; }
  }
  __syncthreads();
  if (tid == 0) {
    float Mm[6][6], Rc[6][6], Rin[6][6];
    for (int i = 0; i < 6; ++i)
      for (int j = 0; j < 6; ++j) {
        Mm[i][j] = Dsh[i * 7 + j] + (i == j ? 1.f : 0.f);
        Rc[i][j] = 0.f; Rin[i][j] = 0.f;
      }
    float logdetM = 0.f;
    for (int i = 0; i < 6; ++i) {
      float s = Mm[i][i];
      for (int k = 0; k < i; ++k) s -= Rc[i][k] * Rc[i][k];
      float rii = sqrtf(s);
      Rc[i][i] = rii;
      logdetM += logf(rii);
      for (int r = i + 1; r < 6; ++r) {
        float s2 = Mm[r][i];
        for (int k = 0; k < i; ++k) s2 -= Rc[r][k] * Rc[i][k];
        Rc[r][i] = s2 / rii;
      }
    }
    logdetM *= 2.f;
    for (int j = 0; j < 6; ++j) {
      Rin[j][j] = 1.f / Rc[j][j];
      for (int i = j + 1; i < 6; ++i) {
        float s3 = 0.f;
        for (int k = j; k < i; ++k) s3 += Rc[i][k] * Rin[k][j];
        Rin[i][j] = -s3 / Rc[i][i];
      }
    }
    for (int i = 0; i < 6; ++i)
      for (int j = 0; j < 6; ++j) {
        float s4 = 0.f;
        for (int k = 0; k < 6; ++k) s4 += Rin[k][i] * Rin[k][j];
        Minv[c * 36 + i * 6 + j] = s4;
      }
    for (int j = 0; j < 6; ++j) svec[c * 6 + j] = Dsh[j * 7 + 6];
    hbuf[c] = Dsh[48];
    biasv[c] = S[3] - 0.5f * (S[9] + logdetM);
  }
}

extern "C" void kernel_launch(void* const* d_in, const int* in_sizes, int n_in,
                              void* d_out, int out_size, void* d_ws, size_t ws_size,
                              hipStream_t stream) {
  const float* Xs   = (const float*)d_in[0];
  const float* Xq   = (const float*)d_in[2];
  const float* m    = (const float*)d_in[3];
  const float* kap  = (const float*)d_in[4];
  const float* nu   = (const float*)d_in[5];
  const float* diag = (const float*)d_in[6];
  const float* low  = (const float*)d_in[7];
  float* ws = (float*)d_ws;

  float* S    = ws + OFF_S;
  float* L    = ws + OFF_L;
  float* W    = ws + OFF_W;
  float* TMP  = ws + OFF_TMP;
  float* Ub   = ws + OFF_UB;
  float* YY   = ws + OFF_YY;   // rows 0..511 = UWp, rows 512.. = Y
  float* Minv = ws + OFF_MINV;
  float* bias = ws + OFF_BIAS;
  float* hb   = ws + OFF_H;
  float* sv   = ws + OFF_SV;

  hipLaunchKernelGGL(k_prep, dim3(1089), dim3(256), 0, stream,
                     diag, low, Xs, m, kap, nu, L, W, Ub, S);
  hipLaunchKernelGGL(k_inv128, dim3(4), dim3(256), 0, stream, L, W);
  // final doubling level n = 256: W[256..,0..] = -W_C @ (L_B @ W_A)
  {
    int n = 256, g = n / 32;
    hipLaunchKernelGGL(k_nn, dim3(g, g), dim3(256), 0, stream,
                       L, D, n * D, W, D, 0, TMP, n, 0, n, 1.0f);
    hipLaunchKernelGGL(k_nn, dim3(g, g), dim3(256), 0, stream,
                       W, D, n * (D + 1), TMP, n, 0, W, D, n * D, n, -1.0f);
  }
  // YY = [Ubp; Xq] @ W^T  (2560 x 512 x 512, triangular-clipped)
  hipLaunchKernelGGL(HIP_KERNEL_NAME(k_big<0>), dim3(40, 8), dim3(256), 0, stream,
                     Ub, Xq, 512, W, YY, 512, D, 1,
                     (const float*)nullptr, (const float*)nullptr, (const float*)nullptr,
                     (const float*)nullptr, (const float*)nullptr, (float*)nullptr);
  hipLaunchKernelGGL(k_msmall, dim3(NC), dim3(256), 0, stream, YY, S, Minv, bias, hb, sv);
  // out = epilogue( Y @ UWp^T )  (2048 x 512 x 512, fused aq/quad/log1p)
  hipLaunchKernelGGL(HIP_KERNEL_NAME(k_big<1>), dim3(32, 8), dim3(256), 0, stream,
                     YY + (size_t)512 * D, YY + (size_t)512 * D, 1 << 30, YY,
                     (float*)nullptr, 0, D, 0,
                     sv, Minv, bias, hb, S, (float*)d_out);
}